// Round 16
// baseline (240.656 us; speedup 1.0000x reference)
//
#include <hip/hip_runtime.h>

typedef __attribute__((ext_vector_type(8))) short bf16x8;
typedef __attribute__((ext_vector_type(4))) float f32x4;

// Operand-swapped GEMM: D^T = W (A-operand) * h^T (B-operand).
// r16: 6 waves = {L1,L2,L3} x 2 stripe-pairs. KEY: B-operand fragments are
// STRIPE-INVARIANT (depend only on batch row + k-chunk), so a wave computing
// 2 output stripes reads the same 2-4 b128 values and applies per-stripe
// weight fragments (VGPR-resident, free). Per-CU-phase LDS reads 40 -> 20
// with MFMA count and per-stripe arithmetic bit-identical to r14.
#define MFMA(a, b, c) __builtin_amdgcn_mfma_f32_16x16x32_bf16((a), (b), (c), 0, 0, 0)

#define TANH_SCALE 2.8853900817779268f   // 2*log2(e); folded into weights

__device__ __forceinline__ short f2bf(float f) {
    union { float f; unsigned u; } v; v.f = f;
    unsigned r = v.u + 0x7fffu + ((v.u >> 16) & 1u);   // RNE
    return (short)(r >> 16);
}
__device__ __forceinline__ float bf2f(short h) {
    union { unsigned u; float f; } v;
    v.u = ((unsigned)(unsigned short)h) << 16;
    return v.f;
}
__device__ __forceinline__ void wsplit(float w, short& hi, short& lo) {
    hi = f2bf(w);
    lo = f2bf(w - bf2f(hi));
}
// tanh on a PRESCALED accumulator s = 2*log2(e)*y:  tanh(y) = 1 - 2/(2^s + 1)
__device__ __forceinline__ float tanh_ps(float s) {
    float z = __builtin_amdgcn_exp2f(s);
    return fmaf(-2.0f, __builtin_amdgcn_rcpf(z + 1.0f), 1.0f);
}
__device__ __forceinline__ unsigned cvt_pk_bf16(float a, float b) {
    unsigned r;
    asm("v_cvt_pk_bf16_f32 %0, %1, %2" : "=v"(r) : "v"(a), "v"(b));
    return r;
}

// weight fragment pair (hi + bf16 residual) of SCALED weight, zero-padded
__device__ __forceinline__ void makeA2(const float* __restrict__ W, int jrow, int kbase,
                                       bf16x8& Ahi, bf16x8& Alo) {
#pragma unroll
    for (int i = 0; i < 8; ++i) {
        int m = kbase + i;
        short h = 0, l = 0;
        if (jrow < 50 && m < 50) wsplit(W[jrow * 50 + m] * TANH_SCALE, h, l);
        Ahi[i] = h; Alo[i] = l;
    }
}

// --- LDS h tile: [16 batch][128 slot] bf16 (256B rows); cols 0-63 used.
// XOR-swizzle bits 4-7 of byte-in-row with row (bijective). Offsets are
// byte-identical to r13/r14 (lo half unused).
__device__ __forceinline__ int swz(int row, int byteInRow) {
    return (row << 8) + (byteInRow ^ ((row & 15) << 4));
}
__device__ __forceinline__ bf16x8 ldsO(const short* hall, int off) {
    return *(const bf16x8*)((const char*)hall + off);
}
__device__ __forceinline__ float ldsR(const short* buf, int row, int col) {
    return bf2f(*(const short*)((const char*)buf + swz(row, col << 1)));
}

// store 4 consecutive hidden cols (single bf16) at precomputed offset.
__device__ __forceinline__ void storeH(short* hall, int off, float t0, float t1, float t2, float t3) {
    uint2 hv;
    hv.x = cvt_pk_bf16(t0, t1);
    hv.y = cvt_pk_bf16(t2, t3);
    *(uint2*)((char*)hall + off) = hv;
}
__device__ __forceinline__ void storeZ(short* hall, int off) {
    uint2 zz; zz.x = 0u; zz.y = 0u;
    *(uint2*)((char*)hall + off) = zz;
}

// One phase. Wave roles: lay 0 = L1 (2 reads, 8 MFMAs in 4 chains of 2),
// lay 1/2 = L2/L3 (4 reads, 12 MFMAs in 4 chains of 3). Each wave covers TWO
// stripes (suffix A/B weight sets) from the SAME B-operand reads. Per-stripe
// chain structure/order is bit-identical to r14. ONE barrier at phase end.
template<bool ZOUT>
__device__ __forceinline__ void phaseP(
    short* hall, int lay,
    int rIa, int rIb, int rSa, int rSb, int woA, int woB,
    const float* xrow, int bcol,
    const f32x4& bvA, const f32x4& bvB, const f32x4& w1fA, const f32x4& w1fB,
    const bf16x8& AIh0, const bf16x8& AIh1,   // stripe A: input-hi weights (L2/L3)
    const bf16x8& AHh0, const bf16x8& AHh1, const bf16x8& AHl0, const bf16x8& AHl1,
    const bf16x8& BIh0, const bf16x8& BIh1,   // stripe B weight set
    const bf16x8& BHh0, const bf16x8& BHh1, const bf16x8& BHl0, const bf16x8& BHl1,
    const f32x4& zc)
{
    if (lay == 0) {
        float xf = xrow[bcol];
        f32x4 cA, cB;
#pragma unroll
        for (int r = 0; r < 4; ++r) {
            cA[r] = fmaf(w1fA[r], xf, bvA[r]);
            cB[r] = fmaf(w1fB[r], xf, bvB[r]);
        }
        bf16x8 s0 = ldsO(hall, rSa), s1 = ldsO(hall, rSb);
        // per stripe: c0 = Hh0*s0 + Hl0*s0 ; c1 = Hh1*s1 + Hl1*s1  (r14 order)
        f32x4 a0 = MFMA(AHh0, s0, cA);
        f32x4 b0 = MFMA(BHh0, s0, cB);
        f32x4 a1 = MFMA(AHh1, s1, zc);
        f32x4 b1 = MFMA(BHh1, s1, zc);
        a0 = MFMA(AHl0, s0, a0);
        b0 = MFMA(BHl0, s0, b0);
        a1 = MFMA(AHl1, s1, a1);
        b1 = MFMA(BHl1, s1, b1);
        storeH(hall, woA, tanh_ps(a0[0] + a1[0]), tanh_ps(a0[1] + a1[1]),
                          tanh_ps(a0[2] + a1[2]), tanh_ps(a0[3] + a1[3]));
        storeH(hall, woB, tanh_ps(b0[0] + b1[0]), tanh_ps(b0[1] + b1[1]),
                          tanh_ps(b0[2] + b1[2]), tanh_ps(b0[3] + b1[3]));
    } else {
        bf16x8 i0 = ldsO(hall, rIa), i1 = ldsO(hall, rIb);
        bf16x8 s0 = ldsO(hall, rSa), s1 = ldsO(hall, rSb);
        // per stripe (r14 order): c0 = Ih0*i0 + Hh0*s0 + Hl0*s0
        //                         c1 = Ih1*i1 + Hh1*s1 + Hl1*s1
        f32x4 a0 = MFMA(AIh0, i0, bvA);
        f32x4 b0 = MFMA(BIh0, i0, bvB);
        f32x4 a1 = MFMA(AIh1, i1, zc);
        f32x4 b1 = MFMA(BIh1, i1, zc);
        a0 = MFMA(AHh0, s0, a0);
        b0 = MFMA(BHh0, s0, b0);
        a1 = MFMA(AHh1, s1, a1);
        b1 = MFMA(BHh1, s1, b1);
        a0 = MFMA(AHl0, s0, a0);
        b0 = MFMA(BHl0, s0, b0);
        a1 = MFMA(AHl1, s1, a1);
        b1 = MFMA(BHl1, s1, b1);
        if (ZOUT) {
            storeZ(hall, woA);
            storeZ(hall, woB);
        } else {
            storeH(hall, woA, tanh_ps(a0[0] + a1[0]), tanh_ps(a0[1] + a1[1]),
                              tanh_ps(a0[2] + a1[2]), tanh_ps(a0[3] + a1[3]));
            storeH(hall, woB, tanh_ps(b0[0] + b1[0]), tanh_ps(b0[1] + b1[1]),
                              tanh_ps(b0[2] + b1[2]), tanh_ps(b0[3] + b1[3]));
        }
    }
    __syncthreads();
}

__global__ __launch_bounds__(384, 1)
void rnn3_kernel(const float* __restrict__ x,
                 const float* __restrict__ Wih1, const float* __restrict__ Whh1,
                 const float* __restrict__ bih1, const float* __restrict__ bhh1,
                 const float* __restrict__ Wih2, const float* __restrict__ Whh2,
                 const float* __restrict__ bih2, const float* __restrict__ bhh2,
                 const float* __restrict__ Wih3, const float* __restrict__ Whh3,
                 const float* __restrict__ bih3, const float* __restrict__ bhh3,
                 const float* __restrict__ Wfc,  const float* __restrict__ bfc,
                 float* __restrict__ out)
{
    // fused state buffer: region r = buf*2 + parity (buf: 0=h1, 1=h2, 2=h3),
    // each region 4096 bytes = [16][128] bf16 swizzled tile (cols 0-63 used).
    __shared__ __align__(16) short hall[6][2048];
    __shared__ float xls[514 * 17 + 8];   // x f32 stride-17; drain tail zeroed

    const int tid  = threadIdx.x;
    const int lane = tid & 63;
    const int w    = tid >> 6;        // 0..5
    const int lay  = w >> 1;          // 0 = L1, 1 = L2, 2 = L3
    const int sp   = w & 1;           // stripe pair: stripes 2sp, 2sp+1
    const int g    = lane >> 4;
    const int l15  = lane & 15;
    const int bcol = l15;             // batch row
    const int sA   = sp << 1, sB = sA | 1;           // the two stripes
    const int jrowA = (sA << 4) | l15, jrowB = (sB << 4) | l15;
    const int joutA = (sA << 4) + (g << 2), joutB = (sB << 4) + (g << 2);
    const int b0   = blockIdx.x * 16;

    // ---- zero-init all h regions (h(-1)=0 + fill safety) ----
    { int* z = (int*)hall; for (int k = tid; k < 6144; k += 384) z[k] = 0; }

    // ---- stage x as f32 [t][b] (stride 17); zero the drain tail ----
    {
        const float4* xg = (const float4*)(x + (size_t)b0 * 512);
        for (int idx = tid; idx < 2048; idx += 384) {
            float4 v = xg[idx];
            int b = idx >> 7, t0 = (idx & 127) << 2;
            xls[(t0 + 0) * 17 + b] = v.x;
            xls[(t0 + 1) * 17 + b] = v.y;
            xls[(t0 + 2) * 17 + b] = v.z;
            xls[(t0 + 3) * 17 + b] = v.w;
        }
        if (tid < 42) xls[512 * 17 + tid] = 0.0f;   // covers phases 512/513 reads
    }

    // ---- per-wave weights for BOTH stripes (prescaled by 2*log2(e)) ----
    const float* WI; const float* WH; const float* bi; const float* bh;
    if (lay == 0)      { WI = Wih1; WH = Whh1; bi = bih1; bh = bhh1; }
    else if (lay == 1) { WI = Wih2; WH = Whh2; bi = bih2; bh = bhh2; }
    else               { WI = Wih3; WH = Whh3; bi = bih3; bh = bhh3; }

    bf16x8 zf8 = {0,0,0,0,0,0,0,0};
    bf16x8 AIh0 = zf8, AIh1 = zf8, BIh0 = zf8, BIh1 = zf8;
    bf16x8 AHh0, AHh1, AHl0, AHl1, BHh0, BHh1, BHl0, BHl1;
    makeA2(WH, jrowA, (g << 3),      AHh0, AHl0);
    makeA2(WH, jrowA, 32 + (g << 3), AHh1, AHl1);
    makeA2(WH, jrowB, (g << 3),      BHh0, BHl0);
    makeA2(WH, jrowB, 32 + (g << 3), BHh1, BHl1);
    if (lay != 0) {
        bf16x8 d0, d1;   // input-side lo residual dropped (r12 design)
        makeA2(WI, jrowA, (g << 3),      AIh0, d0);
        makeA2(WI, jrowA, 32 + (g << 3), AIh1, d1);
        makeA2(WI, jrowB, (g << 3),      BIh0, d0);
        makeA2(WI, jrowB, 32 + (g << 3), BIh1, d1);
    }

    f32x4 bvA, bvB, w1fA, w1fB;
#pragma unroll
    for (int r = 0; r < 4; ++r) {
        int jA = joutA + r, jB = joutB + r;
        bool vA = jA < 50, vB = jB < 50;
        bvA[r]  = vA ? ((bi[jA] + bh[jA]) * TANH_SCALE) : 0.0f;
        bvB[r]  = vB ? ((bi[jB] + bh[jB]) * TANH_SCALE) : 0.0f;
        w1fA[r] = (lay == 0 && vA) ? (Wih1[jA] * TANH_SCALE) : 0.0f;
        w1fB[r] = (lay == 0 && vB) ? (Wih1[jB] * TANH_SCALE) : 0.0f;
    }
    const f32x4 zc = {0.f, 0.f, 0.f, 0.f};

    // ---- loop-invariant byte offsets (stripe-invariant reads!) ----
    const int o0 = swz(bcol, (0 << 6) + (g << 4));   // kblk 0
    const int o1 = swz(bcol, (1 << 6) + (g << 4));   // kblk 1
    const int wbA = swz(bcol, joutA << 1);
    const int wbB = swz(bcol, joutB << 1);
    // role buffers: input buf (L2<-h1=0, L3<-h2=1), state buf = lay
    const int inb = (lay == 2) ? 1 : 0;
    const int stb = lay;
    // A-phase: read parity 1, write parity 0.  B-phase: opposite.
    const int A_Ia = (inb * 2 + 1) * 4096 + o0, A_Ib = (inb * 2 + 1) * 4096 + o1;
    const int A_Sa = (stb * 2 + 1) * 4096 + o0, A_Sb = (stb * 2 + 1) * 4096 + o1;
    const int B_Ia = (inb * 2 + 0) * 4096 + o0, B_Ib = (inb * 2 + 0) * 4096 + o1;
    const int B_Sa = (stb * 2 + 0) * 4096 + o0, B_Sb = (stb * 2 + 0) * 4096 + o1;
    const int A_wA = (lay * 2 + 0) * 4096 + wbA, A_wB = (lay * 2 + 0) * 4096 + wbB;
    const int B_wA = (lay * 2 + 1) * 4096 + wbA, B_wB = (lay * 2 + 1) * 4096 + wbB;

    __syncthreads();   // x staged, h zeroed

    // phase i: reads parity (i+1)&1, writes parity i&1 (r14 schedule).
    // phase 0 (A): L1(0) real; L2/L3 write zeros (= h(-1) states)
    phaseP<true>(&hall[0][0], lay, A_Ia, A_Ib, A_Sa, A_Sb, A_wA, A_wB,
                 &xls[0], bcol, bvA, bvB, w1fA, w1fB,
                 AIh0, AIh1, AHh0, AHh1, AHl0, AHl1,
                 BIh0, BIh1, BHh0, BHh1, BHl0, BHl1, zc);
    // phase 1 (B): L1(1), L2(0) real; L3 writes zero
    if (lay == 2) {
        phaseP<true>(&hall[0][0], lay, B_Ia, B_Ib, B_Sa, B_Sb, B_wA, B_wB,
                     &xls[17], bcol, bvA, bvB, w1fA, w1fB,
                     AIh0, AIh1, AHh0, AHh1, AHl0, AHl1,
                     BIh0, BIh1, BHh0, BHh1, BHl0, BHl1, zc);
    } else {
        phaseP<false>(&hall[0][0], lay, B_Ia, B_Ib, B_Sa, B_Sb, B_wA, B_wB,
                      &xls[17], bcol, bvA, bvB, w1fA, w1fB,
                      AIh0, AIh1, AHh0, AHh1, AHl0, AHl1,
                      BIh0, BIh1, BHh0, BHh1, BHl0, BHl1, zc);
    }

    // main phases 2..511 (manual 2x unroll, compile-time parities)
    for (int i = 2; i < 512; i += 2) {
        phaseP<false>(&hall[0][0], lay, A_Ia, A_Ib, A_Sa, A_Sb, A_wA, A_wB,
                      &xls[i * 17], bcol, bvA, bvB, w1fA, w1fB,
                      AIh0, AIh1, AHh0, AHh1, AHl0, AHl1,
                      BIh0, BIh1, BHh0, BHh1, BHl0, BHl1, zc);
        phaseP<false>(&hall[0][0], lay, B_Ia, B_Ib, B_Sa, B_Sb, B_wA, B_wB,
                      &xls[(i + 1) * 17], bcol, bvA, bvB, w1fA, w1fB,
                      AIh0, AIh1, AHh0, AHh1, AHl0, AHl1,
                      BIh0, BIh1, BHh0, BHh1, BHl0, BHl1, zc);
    }

    // drain: phase 512 (A): L2(511), L3(510) real; L1 output finite, unused
    phaseP<false>(&hall[0][0], lay, A_Ia, A_Ib, A_Sa, A_Sb, A_wA, A_wB,
                  &xls[512 * 17], bcol, bvA, bvB, w1fA, w1fB,
                  AIh0, AIh1, AHh0, AHh1, AHl0, AHl1,
                  BIh0, BIh1, BHh0, BHh1, BHl0, BHl1, zc);
    // drain: phase 513 (B): L3(511) -> h3 parity 1; others finite, unused
    phaseP<false>(&hall[0][0], lay, B_Ia, B_Ib, B_Sa, B_Sb, B_wA, B_wB,
                  &xls[513 * 17], bcol, bvA, bvB, w1fA, w1fB,
                  AIh0, AIh1, AHh0, AHh1, AHl0, AHl1,
                  BIh0, BIh1, BHh0, BHh1, BHl0, BHl1, zc);

    // ---- FC epilogue: out[b][o] = h3 @ Wfc^T + bfc (h3 single bf16) ----
    if (w < 4) {
        const short* h3f = &hall[5][0];   // h3, parity 1 (phase 513's write)
        int o = (w << 2) | g;             // 0..15, valid < 10
        int b = bcol;
        if (o < 10) {
            float acc = bfc[o];
            for (int k = 0; k < 50; ++k)
                acc += ldsR(h3f, b, k) * Wfc[o * 50 + k];
            out[(size_t)(b0 + b) * 10 + o] = acc;
        }
    }
}

extern "C" void kernel_launch(void* const* d_in, const int* in_sizes, int n_in,
                              void* d_out, int out_size, void* d_ws, size_t ws_size,
                              hipStream_t stream) {
    const float* x    = (const float*)d_in[0];
    const float* Wih1 = (const float*)d_in[1];
    const float* Whh1 = (const float*)d_in[2];
    const float* bih1 = (const float*)d_in[3];
    const float* bhh1 = (const float*)d_in[4];
    const float* Wih2 = (const float*)d_in[5];
    const float* Whh2 = (const float*)d_in[6];
    const float* bih2 = (const float*)d_in[7];
    const float* bhh2 = (const float*)d_in[8];
    const float* Wih3 = (const float*)d_in[9];
    const float* Whh3 = (const float*)d_in[10];
    const float* bih3 = (const float*)d_in[11];
    const float* bhh3 = (const float*)d_in[12];
    const float* Wfc  = (const float*)d_in[13];
    const float* bfc  = (const float*)d_in[14];
    float* out = (float*)d_out;

    dim3 grid(256), block(384);   // 16 batch rows/block; 6 waves = layer x stripe-pair
    hipLaunchKernelGGL(rnn3_kernel, grid, block, 0, stream,
                       x, Wih1, Whh1, bih1, bhh1,
                       Wih2, Whh2, bih2, bhh2,
                       Wih3, Whh3, bih3, bhh3,
                       Wfc, bfc, out);
}

// Round 17
// 188.297 us; speedup vs baseline: 1.2781x; 1.2781x over previous
//
#include <hip/hip_runtime.h>

typedef __attribute__((ext_vector_type(8))) short bf16x8;
typedef __attribute__((ext_vector_type(4))) float f32x4;

// Operand-swapped GEMM: D^T = W (A-operand) * h^T (B-operand).
// r17 = r14 (12 waves = {L1,L2,L3} x 4 stripes, the proven optimum) + a
// 2-stagger pipeline: phase i computes {L1(i), L2(i-2), L3(i-4)} with mod-3
// h buffers. INPUT operands (h1->L2, h2->L3) are PREFETCHED into registers
// one phase early (data is 2 phases old); only STATE reads (24/CU) remain on
// the post-barrier critical path. Per-layer arithmetic bit-identical to r14.
#define MFMA(a, b, c) __builtin_amdgcn_mfma_f32_16x16x32_bf16((a), (b), (c), 0, 0, 0)

#define TANH_SCALE 2.8853900817779268f   // 2*log2(e); folded into weights

__device__ __forceinline__ short f2bf(float f) {
    union { float f; unsigned u; } v; v.f = f;
    unsigned r = v.u + 0x7fffu + ((v.u >> 16) & 1u);   // RNE
    return (short)(r >> 16);
}
__device__ __forceinline__ float bf2f(short h) {
    union { unsigned u; float f; } v;
    v.u = ((unsigned)(unsigned short)h) << 16;
    return v.f;
}
__device__ __forceinline__ void wsplit(float w, short& hi, short& lo) {
    hi = f2bf(w);
    lo = f2bf(w - bf2f(hi));
}
// tanh on a PRESCALED accumulator s = 2*log2(e)*y:  tanh(y) = 1 - 2/(2^s + 1)
__device__ __forceinline__ float tanh_ps(float s) {
    float z = __builtin_amdgcn_exp2f(s);
    return fmaf(-2.0f, __builtin_amdgcn_rcpf(z + 1.0f), 1.0f);
}
__device__ __forceinline__ unsigned cvt_pk_bf16(float a, float b) {
    unsigned r;
    asm("v_cvt_pk_bf16_f32 %0, %1, %2" : "=v"(r) : "v"(a), "v"(b));
    return r;
}

// weight fragment pair (hi + bf16 residual) of SCALED weight, zero-padded
__device__ __forceinline__ void makeA2(const float* __restrict__ W, int jrow, int kbase,
                                       bf16x8& Ahi, bf16x8& Alo) {
#pragma unroll
    for (int i = 0; i < 8; ++i) {
        int m = kbase + i;
        short h = 0, l = 0;
        if (jrow < 50 && m < 50) wsplit(W[jrow * 50 + m] * TANH_SCALE, h, l);
        Ahi[i] = h; Alo[i] = l;
    }
}

// --- LDS h tile: [16 batch][128 slot] bf16 (256B rows); cols 0-63 used.
// XOR-swizzle bits 4-7 of byte-in-row with row (bijective).
__device__ __forceinline__ int swz(int row, int byteInRow) {
    return (row << 8) + (byteInRow ^ ((row & 15) << 4));
}
__device__ __forceinline__ bf16x8 ldsO(const short* hall, int off) {
    return *(const bf16x8*)((const char*)hall + off);
}
__device__ __forceinline__ float ldsR(const short* buf, int row, int col) {
    return bf2f(*(const short*)((const char*)buf + swz(row, col << 1)));
}

// store 4 consecutive hidden cols (single bf16) at precomputed offset.
__device__ __forceinline__ void storeH(short* hall, int off, float t0, float t1, float t2, float t3) {
    uint2 hv;
    hv.x = cvt_pk_bf16(t0, t1);
    hv.y = cvt_pk_bf16(t2, t3);
    *(uint2*)((char*)hall + off) = hv;
}
__device__ __forceinline__ void storeZ(short* hall, int off) {
    uint2 zz; zz.x = 0u; zz.y = 0u;
    *(uint2*)((char*)hall + off) = zz;
}

// One phase. L1 wave: 2 state reads, 4 MFMAs (r14 order), x folded in C-init.
// L2/L3 wave: 2 state reads at head; first 2 MFMAs run on PREFETCHED input
// registers (iR0/iR1); then 4 state MFMAs; then prefetch next phase's input;
// then tanh+store. Z2/Z3: pipeline-fill zero stores. ONE barrier at end.
template<bool Z2, bool Z3>
__device__ __forceinline__ void phaseS(
    short* hall, int lay,
    int sa, int sb, int wo, int pa, int pb,
    bf16x8& iR0, bf16x8& iR1,
    const float* xrow, int bcol,
    const f32x4& bv, const f32x4& w1f,
    const bf16x8& Ih0, const bf16x8& Ih1,
    const bf16x8& Hh0, const bf16x8& Hh1, const bf16x8& Hl0, const bf16x8& Hl1,
    const f32x4& zc)
{
    if (lay == 0) {
        float xf = xrow[bcol];
        f32x4 c1i;
        c1i[0] = fmaf(w1f[0], xf, bv[0]);
        c1i[1] = fmaf(w1f[1], xf, bv[1]);
        c1i[2] = fmaf(w1f[2], xf, bv[2]);
        c1i[3] = fmaf(w1f[3], xf, bv[3]);
        bf16x8 s0 = ldsO(hall, sa), s1 = ldsO(hall, sb);
        f32x4 c0 = MFMA(Hh0, s0, c1i);
        f32x4 c1 = MFMA(Hh1, s1, zc);
        c0 = MFMA(Hl0, s0, c0);
        c1 = MFMA(Hl1, s1, c1);
        float t0 = tanh_ps(c0[0] + c1[0]);
        float t1 = tanh_ps(c0[1] + c1[1]);
        float t2 = tanh_ps(c0[2] + c1[2]);
        float t3 = tanh_ps(c0[3] + c1[3]);
        storeH(hall, wo, t0, t1, t2, t3);
    } else {
        bf16x8 s0 = ldsO(hall, sa), s1 = ldsO(hall, sb);   // state reads (critical)
        f32x4 c0 = MFMA(Ih0, iR0, bv);                     // input: prefetched regs
        f32x4 c1 = MFMA(Ih1, iR1, zc);
        c0 = MFMA(Hh0, s0, c0);
        c1 = MFMA(Hh1, s1, c1);
        c0 = MFMA(Hl0, s0, c0);
        c1 = MFMA(Hl1, s1, c1);
        iR0 = ldsO(hall, pa);                              // prefetch next input
        iR1 = ldsO(hall, pb);
        bool zout = (lay == 1) ? Z2 : Z3;
        if (zout) {
            storeZ(hall, wo);
        } else {
            float t0 = tanh_ps(c0[0] + c1[0]);
            float t1 = tanh_ps(c0[1] + c1[1]);
            float t2 = tanh_ps(c0[2] + c1[2]);
            float t3 = tanh_ps(c0[3] + c1[3]);
            storeH(hall, wo, t0, t1, t2, t3);
        }
    }
    __syncthreads();
}

__global__ __launch_bounds__(768, 1)
void rnn3_kernel(const float* __restrict__ x,
                 const float* __restrict__ Wih1, const float* __restrict__ Whh1,
                 const float* __restrict__ bih1, const float* __restrict__ bhh1,
                 const float* __restrict__ Wih2, const float* __restrict__ Whh2,
                 const float* __restrict__ bih2, const float* __restrict__ bhh2,
                 const float* __restrict__ Wih3, const float* __restrict__ Whh3,
                 const float* __restrict__ bih3, const float* __restrict__ bhh3,
                 const float* __restrict__ Wfc,  const float* __restrict__ bfc,
                 float* __restrict__ out)
{
    // fused state buffer: region r = buf*3 + slot (buf: 0=h1, 1=h2, 2=h3;
    // slot = phase mod 3). Each region 4096 B = [16][128] bf16 swizzled tile.
    __shared__ __align__(16) short hall[9][2048];
    __shared__ float xls[516 * 17 + 8];   // x f32 stride-17; drain tail zeroed

    const int tid  = threadIdx.x;
    const int lane = tid & 63;
    const int w    = tid >> 6;        // 0..11
    const int stripe  = w & 3;        // 16-col output stripe
    const int lay     = w >> 2;       // 0 = L1, 1 = L2, 2 = L3
    const int g    = lane >> 4;
    const int l15  = lane & 15;
    const int jrow = (stripe << 4) | l15;      // weight row (output col)
    const int bcol = l15;                      // batch row
    const int jout0 = (stripe << 4) + (g << 2);
    const int b0   = blockIdx.x * 16;

    // ---- zero-init all h regions (h(-1)=0 + fill safety) ----
    { int* z = (int*)hall; for (int k = tid; k < 9216; k += 768) z[k] = 0; }

    // ---- stage x as f32 [t][b] (stride 17); zero the drain tail ----
    {
        const float4* xg = (const float4*)(x + (size_t)b0 * 512);
        for (int idx = tid; idx < 2048; idx += 768) {
            float4 v = xg[idx];
            int b = idx >> 7, t0 = (idx & 127) << 2;
            xls[(t0 + 0) * 17 + b] = v.x;
            xls[(t0 + 1) * 17 + b] = v.y;
            xls[(t0 + 2) * 17 + b] = v.z;
            xls[(t0 + 3) * 17 + b] = v.w;
        }
        if (tid < 76) xls[512 * 17 + tid] = 0.0f;   // covers phases 512..515 reads
    }

    // ---- per-wave weights (prescaled by 2*log2(e)) ----
    const float* WI; const float* WH; const float* bi; const float* bh;
    if (lay == 0)      { WI = Wih1; WH = Whh1; bi = bih1; bh = bhh1; }
    else if (lay == 1) { WI = Wih2; WH = Whh2; bi = bih2; bh = bhh2; }
    else               { WI = Wih3; WH = Whh3; bi = bih3; bh = bhh3; }

    bf16x8 zf8 = {0,0,0,0,0,0,0,0};
    bf16x8 Ih0 = zf8, Ih1 = zf8;
    bf16x8 Hh0, Hl0, Hh1, Hl1;
    makeA2(WH, jrow, (g << 3),      Hh0, Hl0);
    makeA2(WH, jrow, 32 + (g << 3), Hh1, Hl1);
    if (lay != 0) {
        bf16x8 d0, d1;   // input-side lo residual dropped (r12 design)
        makeA2(WI, jrow, (g << 3),      Ih0, d0);
        makeA2(WI, jrow, 32 + (g << 3), Ih1, d1);
    }

    f32x4 bv, w1f;
#pragma unroll
    for (int r = 0; r < 4; ++r) {
        int j = jout0 + r;
        bool v = j < 50;
        bv[r]  = v ? ((bi[j] + bh[j]) * TANH_SCALE) : 0.0f;
        w1f[r] = (lay == 0 && v) ? (Wih1[j] * TANH_SCALE) : 0.0f;
    }
    const f32x4 zc = {0.f, 0.f, 0.f, 0.f};

    // ---- loop-invariant byte offsets, one set per phase parity p = i mod 3 ----
    // state slot = (p+2)%3 (written last phase); write slot = p;
    // prefetch slot = (p+2)%3 (input data written 1 phase ago, consumed next).
    const int o0 = swz(bcol, (0 << 6) + (g << 4));
    const int o1 = swz(bcol, (1 << 6) + (g << 4));
    const int wbyte = swz(bcol, jout0 << 1);
    const int inb = (lay == 2) ? 1 : 0;   // input buf: L2<-h1, L3<-h2
    const int stb = lay;                  // state buf = own layer
#define REG(buf, slot) (((buf) * 3 + (slot)) * 4096)
    const int sa0 = REG(stb, 2) + o0, sb0 = REG(stb, 2) + o1;   // p=0
    const int sa1 = REG(stb, 0) + o0, sb1 = REG(stb, 0) + o1;   // p=1
    const int sa2 = REG(stb, 1) + o0, sb2 = REG(stb, 1) + o1;   // p=2
    const int wo0 = REG(lay, 0) + wbyte;
    const int wo1 = REG(lay, 1) + wbyte;
    const int wo2 = REG(lay, 2) + wbyte;
    const int pa0 = REG(inb, 2) + o0, pb0 = REG(inb, 2) + o1;
    const int pa1 = REG(inb, 0) + o0, pb1 = REG(inb, 0) + o1;
    const int pa2 = REG(inb, 1) + o0, pb2 = REG(inb, 1) + o1;
#undef REG

    bf16x8 iR0 = zf8, iR1 = zf8;   // prefetched input regs (phase 0: zeros ok)

    __syncthreads();   // x staged, h zeroed

    short* H = &hall[0][0];
    // ---- fill: phases 0..5 (Z2 at 0,1; Z3 at 0..3) ----
    phaseS<true, true>(H, lay, sa0, sb0, wo0, pa0, pb0, iR0, iR1,
                       &xls[0 * 17], bcol, bv, w1f, Ih0, Ih1, Hh0, Hh1, Hl0, Hl1, zc);
    phaseS<true, true>(H, lay, sa1, sb1, wo1, pa1, pb1, iR0, iR1,
                       &xls[1 * 17], bcol, bv, w1f, Ih0, Ih1, Hh0, Hh1, Hl0, Hl1, zc);
    phaseS<false, true>(H, lay, sa2, sb2, wo2, pa2, pb2, iR0, iR1,
                        &xls[2 * 17], bcol, bv, w1f, Ih0, Ih1, Hh0, Hh1, Hl0, Hl1, zc);
    phaseS<false, true>(H, lay, sa0, sb0, wo0, pa0, pb0, iR0, iR1,
                        &xls[3 * 17], bcol, bv, w1f, Ih0, Ih1, Hh0, Hh1, Hl0, Hl1, zc);
    phaseS<false, false>(H, lay, sa1, sb1, wo1, pa1, pb1, iR0, iR1,
                         &xls[4 * 17], bcol, bv, w1f, Ih0, Ih1, Hh0, Hh1, Hl0, Hl1, zc);
    phaseS<false, false>(H, lay, sa2, sb2, wo2, pa2, pb2, iR0, iR1,
                         &xls[5 * 17], bcol, bv, w1f, Ih0, Ih1, Hh0, Hh1, Hl0, Hl1, zc);

    // ---- main loop: phases 6..515, 3 per iteration (compile-time parities) ----
    const float* xp = &xls[6 * 17];
    for (int it = 0; it < 170; ++it) {
        phaseS<false, false>(H, lay, sa0, sb0, wo0, pa0, pb0, iR0, iR1,
                             xp, bcol, bv, w1f, Ih0, Ih1, Hh0, Hh1, Hl0, Hl1, zc);
        phaseS<false, false>(H, lay, sa1, sb1, wo1, pa1, pb1, iR0, iR1,
                             xp + 17, bcol, bv, w1f, Ih0, Ih1, Hh0, Hh1, Hl0, Hl1, zc);
        phaseS<false, false>(H, lay, sa2, sb2, wo2, pa2, pb2, iR0, iR1,
                             xp + 34, bcol, bv, w1f, Ih0, Ih1, Hh0, Hh1, Hl0, Hl1, zc);
        xp += 51;
    }
    // pipeline: L1 done at phase 511 (garbage 512-515 finite); L2 real through
    // phase 513 (step 511); L3 real through phase 515 (step 511).

    // ---- FC epilogue: out[b][o] = h3 @ Wfc^T + bfc (h3 single bf16) ----
    // final h3 (step 511) written at phase 515, p=2 -> region lay*3+2 = 8.
    if (w < 4) {
        const short* h3f = &hall[8][0];
        int o = (w << 2) | g;             // 0..15, valid < 10
        int b = bcol;
        if (o < 10) {
            float acc = bfc[o];
            for (int k = 0; k < 50; ++k)
                acc += ldsR(h3f, b, k) * Wfc[o * 50 + k];
            out[(size_t)(b0 + b) * 10 + o] = acc;
        }
    }
}

extern "C" void kernel_launch(void* const* d_in, const int* in_sizes, int n_in,
                              void* d_out, int out_size, void* d_ws, size_t ws_size,
                              hipStream_t stream) {
    const float* x    = (const float*)d_in[0];
    const float* Wih1 = (const float*)d_in[1];
    const float* Whh1 = (const float*)d_in[2];
    const float* bih1 = (const float*)d_in[3];
    const float* bhh1 = (const float*)d_in[4];
    const float* Wih2 = (const float*)d_in[5];
    const float* Whh2 = (const float*)d_in[6];
    const float* bih2 = (const float*)d_in[7];
    const float* bhh2 = (const float*)d_in[8];
    const float* Wih3 = (const float*)d_in[9];
    const float* Whh3 = (const float*)d_in[10];
    const float* bih3 = (const float*)d_in[11];
    const float* bhh3 = (const float*)d_in[12];
    const float* Wfc  = (const float*)d_in[13];
    const float* bfc  = (const float*)d_in[14];
    float* out = (float*)d_out;

    dim3 grid(256), block(768);   // 16 batch rows/block; 12 waves = layer x stripe
    hipLaunchKernelGGL(rnn3_kernel, grid, block, 0, stream,
                       x, Wih1, Whh1, bih1, bhh1,
                       Wih2, Whh2, bih2, bhh2,
                       Wih3, Whh3, bih3, bhh3,
                       Wfc, bfc, out);
}

// Round 18
// 185.649 us; speedup vs baseline: 1.2963x; 1.0143x over previous
//
#include <hip/hip_runtime.h>

typedef __attribute__((ext_vector_type(8))) short bf16x8;
typedef __attribute__((ext_vector_type(4))) float f32x4;

// Operand-swapped GEMM: D^T = W (A-operand) * h^T (B-operand).
// 12 waves = {L1,L2,L3} x 4 col-stripes, ONE barrier/phase (r10+ proven).
// h states are SINGLE bf16 (no lo residual); weights keep hi/lo split,
// x folded in fp32, accumulation fp32. This is the r14 kernel (184.7 us),
// reverted to after r15-r17 structural variants (fewer LDS reads, wave
// merges, register prefetch) all measured flat-to-worse: the phase time is
// set by barrier resync + slowest-wave program length at 3 waves/SIMD, not
// by LDS traffic. 512 serial phases x ~960 cyc is the structural floor of
// this design space on CDNA4 (no sub-block barrier primitive exists).
#define MFMA(a, b, c) __builtin_amdgcn_mfma_f32_16x16x32_bf16((a), (b), (c), 0, 0, 0)

#define TANH_SCALE 2.8853900817779268f   // 2*log2(e); folded into weights

__device__ __forceinline__ short f2bf(float f) {
    union { float f; unsigned u; } v; v.f = f;
    unsigned r = v.u + 0x7fffu + ((v.u >> 16) & 1u);   // RNE
    return (short)(r >> 16);
}
__device__ __forceinline__ float bf2f(short h) {
    union { unsigned u; float f; } v;
    v.u = ((unsigned)(unsigned short)h) << 16;
    return v.f;
}
__device__ __forceinline__ void wsplit(float w, short& hi, short& lo) {
    hi = f2bf(w);
    lo = f2bf(w - bf2f(hi));
}
// tanh on a PRESCALED accumulator s = 2*log2(e)*y:  tanh(y) = 1 - 2/(2^s + 1)
__device__ __forceinline__ float tanh_ps(float s) {
    float z = __builtin_amdgcn_exp2f(s);
    return fmaf(-2.0f, __builtin_amdgcn_rcpf(z + 1.0f), 1.0f);
}
__device__ __forceinline__ unsigned cvt_pk_bf16(float a, float b) {
    unsigned r;
    asm("v_cvt_pk_bf16_f32 %0, %1, %2" : "=v"(r) : "v"(a), "v"(b));
    return r;
}

// weight fragment pair (hi + bf16 residual) of SCALED weight, zero-padded
__device__ __forceinline__ void makeA2(const float* __restrict__ W, int jrow, int kbase,
                                       bf16x8& Ahi, bf16x8& Alo) {
#pragma unroll
    for (int i = 0; i < 8; ++i) {
        int m = kbase + i;
        short h = 0, l = 0;
        if (jrow < 50 && m < 50) wsplit(W[jrow * 50 + m] * TANH_SCALE, h, l);
        Ahi[i] = h; Alo[i] = l;
    }
}

// --- LDS h tile: [16 batch][128 hidden-slot] bf16 (256B rows); cols 0-63 used.
// XOR-swizzle bits 4-7 of byte-in-row with row (bijective).
__device__ __forceinline__ int swz(int row, int byteInRow) {
    return (row << 8) + (byteInRow ^ ((row & 15) << 4));
}
__device__ __forceinline__ bf16x8 ldsO(const short* hall, int off) {
    return *(const bf16x8*)((const char*)hall + off);
}
__device__ __forceinline__ float ldsR(const short* buf, int row, int col) {
    return bf2f(*(const short*)((const char*)buf + swz(row, col << 1)));
}

// store 4 consecutive hidden cols (single bf16) at precomputed offset.
__device__ __forceinline__ void storeH(short* hall, int off, float t0, float t1, float t2, float t3) {
    uint2 hv;
    hv.x = cvt_pk_bf16(t0, t1);
    hv.y = cvt_pk_bf16(t2, t3);
    *(uint2*)((char*)hall + off) = hv;
}
__device__ __forceinline__ void storeZ(short* hall, int off) {
    uint2 zz; zz.x = 0u; zz.y = 0u;
    *(uint2*)((char*)hall + off) = zz;
}

// One phase, role-dispatched; ALL addresses are precomputed byte offsets.
// L2/L3: 4 reads (input hi, state hi), 6 MFMAs in 2 chains of 3.
// L1: 2 reads, 4 MFMAs in chains of 3+2 (x folded into C-init).
// ONE barrier at phase end (parity/Z scheme identical to r12/r13).
template<bool ZOUT>
__device__ __forceinline__ void phaseX(
    short* hall, int layerid,
    int i0o, int i1o, int s0o, int s1o, int woff,
    const float* xrow, int bcol,
    const f32x4& bv, const f32x4& w1f,
    const bf16x8& Ih0, const bf16x8& Ih1,
    const bf16x8& Hh0, const bf16x8& Hh1, const bf16x8& Hl0, const bf16x8& Hl1,
    const f32x4& zc)
{
    if (layerid == 0) {
        float xf = xrow[bcol];
        f32x4 c1i;
        c1i[0] = fmaf(w1f[0], xf, bv[0]);
        c1i[1] = fmaf(w1f[1], xf, bv[1]);
        c1i[2] = fmaf(w1f[2], xf, bv[2]);
        c1i[3] = fmaf(w1f[3], xf, bv[3]);
        bf16x8 s0 = ldsO(hall, s0o), s1 = ldsO(hall, s1o);
        f32x4 c0 = MFMA(Hh0, s0, c1i);
        f32x4 c1 = MFMA(Hh1, s1, zc);
        c0 = MFMA(Hl0, s0, c0);
        c1 = MFMA(Hl1, s1, c1);
        float t0 = tanh_ps(c0[0] + c1[0]);
        float t1 = tanh_ps(c0[1] + c1[1]);
        float t2 = tanh_ps(c0[2] + c1[2]);
        float t3 = tanh_ps(c0[3] + c1[3]);
        storeH(hall, woff, t0, t1, t2, t3);
    } else {
        bf16x8 i0 = ldsO(hall, i0o), i1 = ldsO(hall, i1o);
        bf16x8 s0 = ldsO(hall, s0o), s1 = ldsO(hall, s1o);
        f32x4 c0 = MFMA(Ih0, i0, bv);
        f32x4 c1 = MFMA(Ih1, i1, zc);
        c0 = MFMA(Hh0, s0, c0);
        c1 = MFMA(Hh1, s1, c1);
        c0 = MFMA(Hl0, s0, c0);
        c1 = MFMA(Hl1, s1, c1);
        if (ZOUT) {
            storeZ(hall, woff);
        } else {
            float t0 = tanh_ps(c0[0] + c1[0]);
            float t1 = tanh_ps(c0[1] + c1[1]);
            float t2 = tanh_ps(c0[2] + c1[2]);
            float t3 = tanh_ps(c0[3] + c1[3]);
            storeH(hall, woff, t0, t1, t2, t3);
        }
    }
    __syncthreads();
}

__global__ __launch_bounds__(768, 1)
void rnn3_kernel(const float* __restrict__ x,
                 const float* __restrict__ Wih1, const float* __restrict__ Whh1,
                 const float* __restrict__ bih1, const float* __restrict__ bhh1,
                 const float* __restrict__ Wih2, const float* __restrict__ Whh2,
                 const float* __restrict__ bih2, const float* __restrict__ bhh2,
                 const float* __restrict__ Wih3, const float* __restrict__ Whh3,
                 const float* __restrict__ bih3, const float* __restrict__ bhh3,
                 const float* __restrict__ Wfc,  const float* __restrict__ bfc,
                 float* __restrict__ out)
{
    // fused state buffer: region r = buf*2 + parity (buf: 0=h1, 1=h2, 2=h3),
    // each region 4096 bytes = [16][128] bf16 swizzled tile (cols 0-63 used).
    __shared__ __align__(16) short hall[6][2048];
    __shared__ float xls[514 * 17 + 8];   // x f32 stride-17; drain tail zeroed

    const int tid  = threadIdx.x;
    const int lane = tid & 63;
    const int w    = tid >> 6;        // 0..11
    const int stripe  = w & 3;        // 16-col output stripe
    const int layerid = w >> 2;       // 0 = L1, 1 = L2, 2 = L3
    const int g    = lane >> 4;
    const int l15  = lane & 15;
    const int jrow = (stripe << 4) | l15;      // weight row (output col)
    const int bcol = l15;                      // batch row
    const int jout0 = (stripe << 4) + (g << 2);
    const int b0   = blockIdx.x * 16;

    // ---- zero-init all h regions (h(-1)=0 + fill safety) ----
    { int* z = (int*)hall; for (int k = tid; k < 6144; k += 768) z[k] = 0; }

    // ---- stage x as f32 [t][b] (stride 17); zero the drain tail ----
    {
        const float4* xg = (const float4*)(x + (size_t)b0 * 512);
        for (int idx = tid; idx < 2048; idx += 768) {
            float4 v = xg[idx];
            int b = idx >> 7, t0 = (idx & 127) << 2;
            xls[(t0 + 0) * 17 + b] = v.x;
            xls[(t0 + 1) * 17 + b] = v.y;
            xls[(t0 + 2) * 17 + b] = v.z;
            xls[(t0 + 3) * 17 + b] = v.w;
        }
        if (tid < 42) xls[512 * 17 + tid] = 0.0f;   // covers phases 512/513 reads
    }

    // ---- per-wave weights (prescaled by 2*log2(e), hi + lo residual) ----
    const float* WI; const float* WH; const float* bi; const float* bh;
    if (layerid == 0)      { WI = Wih1; WH = Whh1; bi = bih1; bh = bhh1; }
    else if (layerid == 1) { WI = Wih2; WH = Whh2; bi = bih2; bh = bhh2; }
    else                   { WI = Wih3; WH = Whh3; bi = bih3; bh = bhh3; }

    bf16x8 zf8 = {0,0,0,0,0,0,0,0};
    bf16x8 Ih0 = zf8, Ih1 = zf8;
    bf16x8 Hh0, Hl0, Hh1, Hl1;
    makeA2(WH, jrow, (g << 3),      Hh0, Hl0);
    makeA2(WH, jrow, 32 + (g << 3), Hh1, Hl1);
    if (layerid != 0) {
        bf16x8 d0, d1;   // input-side lo residual dropped (r12)
        makeA2(WI, jrow, (g << 3),      Ih0, d0);
        makeA2(WI, jrow, 32 + (g << 3), Ih1, d1);
    }

    f32x4 bv, w1f;
#pragma unroll
    for (int r = 0; r < 4; ++r) {
        int j = jout0 + r;
        bool v = j < 50;
        bv[r]  = v ? ((bi[j] + bh[j]) * TANH_SCALE) : 0.0f;
        w1f[r] = (layerid == 0 && v) ? (Wih1[j] * TANH_SCALE) : 0.0f;
    }
    const f32x4 zc = {0.f, 0.f, 0.f, 0.f};

    // ---- loop-invariant byte offsets ----
    const int o0 = swz(bcol, (0 << 6) + (g << 4));   // hi, kblk 0
    const int o1 = swz(bcol, (1 << 6) + (g << 4));   // hi, kblk 1
    const int wbyte = swz(bcol, jout0 << 1);
    // role buffers: input buf (L2<-h1=0, L3<-h2=1), state buf = layerid
    const int inb = (layerid == 2) ? 1 : 0;
    const int stb = layerid;
    const int A_i0 = (inb * 2 + 1) * 4096 + o0, A_i1 = (inb * 2 + 1) * 4096 + o1;
    const int A_s0 = (stb * 2 + 1) * 4096 + o0, A_s1 = (stb * 2 + 1) * 4096 + o1;
    const int B_i0 = (inb * 2 + 0) * 4096 + o0, B_i1 = (inb * 2 + 0) * 4096 + o1;
    const int B_s0 = (stb * 2 + 0) * 4096 + o0, B_s1 = (stb * 2 + 0) * 4096 + o1;
    const int wofA = (layerid * 2 + 0) * 4096 + wbyte;   // write parity 0
    const int wofB = (layerid * 2 + 1) * 4096 + wbyte;   // write parity 1

    __syncthreads();   // x staged, h zeroed

    // phase i: reads parity (i+1)&1, writes parity i&1 (r12 schedule).
    // phase 0 (write par0): L1 real; L2/L3 write zeros (= h(-1) states)
    phaseX<true>(&hall[0][0], layerid, A_i0, A_i1, A_s0, A_s1, wofA,
                 &xls[0], bcol, bv, w1f, Ih0, Ih1, Hh0, Hh1, Hl0, Hl1, zc);
    // phase 1 (write par1): L1, L2 real; L3 zero
    if (layerid == 2) {
        phaseX<true>(&hall[0][0], layerid, B_i0, B_i1, B_s0, B_s1, wofB,
                     &xls[17], bcol, bv, w1f, Ih0, Ih1, Hh0, Hh1, Hl0, Hl1, zc);
    } else {
        phaseX<false>(&hall[0][0], layerid, B_i0, B_i1, B_s0, B_s1, wofB,
                      &xls[17], bcol, bv, w1f, Ih0, Ih1, Hh0, Hh1, Hl0, Hl1, zc);
    }

    // main phases 2..511 (manual 2x unroll, compile-time parities)
    for (int i = 2; i < 512; i += 2) {
        phaseX<false>(&hall[0][0], layerid, A_i0, A_i1, A_s0, A_s1, wofA,
                      &xls[i * 17], bcol, bv, w1f, Ih0, Ih1, Hh0, Hh1, Hl0, Hl1, zc);
        phaseX<false>(&hall[0][0], layerid, B_i0, B_i1, B_s0, B_s1, wofB,
                      &xls[(i + 1) * 17], bcol, bv, w1f, Ih0, Ih1, Hh0, Hh1, Hl0, Hl1, zc);
    }

    // drain: phase 512 (L2(511), L3(510); L1 output finite, unused)
    phaseX<false>(&hall[0][0], layerid, A_i0, A_i1, A_s0, A_s1, wofA,
                  &xls[512 * 17], bcol, bv, w1f, Ih0, Ih1, Hh0, Hh1, Hl0, Hl1, zc);
    // drain: phase 513 (L3(511) -> h3 parity 1)
    phaseX<false>(&hall[0][0], layerid, B_i0, B_i1, B_s0, B_s1, wofB,
                  &xls[513 * 17], bcol, bv, w1f, Ih0, Ih1, Hh0, Hh1, Hl0, Hl1, zc);

    // ---- FC epilogue: out[b][o] = h3 @ Wfc^T + bfc (h3 single bf16) ----
    if (w < 4) {
        const short* h3f = &hall[5][0];   // h3, parity 1 (phase 513's write)
        int o = (w << 2) | g;             // 0..15, valid < 10
        int b = bcol;
        if (o < 10) {
            float acc = bfc[o];
            for (int k = 0; k < 50; ++k)
                acc += ldsR(h3f, b, k) * Wfc[o * 50 + k];
            out[(size_t)(b0 + b) * 10 + o] = acc;
        }
    }
}

extern "C" void kernel_launch(void* const* d_in, const int* in_sizes, int n_in,
                              void* d_out, int out_size, void* d_ws, size_t ws_size,
                              hipStream_t stream) {
    const float* x    = (const float*)d_in[0];
    const float* Wih1 = (const float*)d_in[1];
    const float* Whh1 = (const float*)d_in[2];
    const float* bih1 = (const float*)d_in[3];
    const float* bhh1 = (const float*)d_in[4];
    const float* Wih2 = (const float*)d_in[5];
    const float* Whh2 = (const float*)d_in[6];
    const float* bih2 = (const float*)d_in[7];
    const float* bhh2 = (const float*)d_in[8];
    const float* Wih3 = (const float*)d_in[9];
    const float* Whh3 = (const float*)d_in[10];
    const float* bih3 = (const float*)d_in[11];
    const float* bhh3 = (const float*)d_in[12];
    const float* Wfc  = (const float*)d_in[13];
    const float* bfc  = (const float*)d_in[14];
    float* out = (float*)d_out;

    dim3 grid(256), block(768);   // 16 batch rows/block; 12 waves = layer x stripe
    hipLaunchKernelGGL(rnn3_kernel, grid, block, 0, stream,
                       x, Wih1, Whh1, bih1, bhh1,
                       Wih2, Whh2, bih2, bhh2,
                       Wih3, Whh3, bih3, bhh3,
                       Wfc, bfc, out);
}